// Round 1
// baseline (855.676 us; speedup 1.0000x reference)
//
#include <hip/hip_runtime.h>
#include <stdint.h>

// Problem constants (fixed by reference setup_inputs)
#define BATCH 8
#define NPTS  65536
#define NCLS  80
#define NANCH (BATCH * NPTS)          // 524288
#define TOPK  4096
#define CONF  4.0f
#define NMSTH 0.5f

// ws layout (bytes)
static constexpr size_t OFF_CNT    = 0;                         // int cnt (64B pad)
static constexpr size_t OFF_KEYS   = 64;                        // u64 keys_raw[8192]
static constexpr size_t OFF_SORTED = OFF_KEYS + 8192 * 8;       // u64 keys_sorted[4096]
static constexpr size_t OFF_BOX    = OFF_SORTED + 4096 * 8;     // float4 topbox[4096] (16B aligned)
static constexpr size_t OFF_CAT    = OFF_BOX + 4096 * 16;       // int topcat[4096]
static constexpr size_t OFF_CLS    = OFF_CAT + 4096 * 4;        // int topcls[4096]
static constexpr size_t OFF_SCORE  = OFF_CLS + 4096 * 4;        // float topscore[4096]
static constexpr size_t OFF_IMG    = OFF_SCORE + 4096 * 4;      // int topimg[4096]
static constexpr size_t OFF_MASK   = OFF_IMG + 4096 * 4;        // u64 mask[4096*64] = 2MB

// ---------------- Kernel 1: per-anchor max/argmax + confidence compaction ----
// key = (sortable(score) << 32) | ~idx  -> descending key = score desc, idx asc
__global__ __launch_bounds__(256) void k_score(const float* __restrict__ logits,
                                               int* __restrict__ cnt,
                                               unsigned long long* __restrict__ keys) {
    int a = blockIdx.x * 256 + threadIdx.x;   // grid exactly covers NANCH
    const float4* p = (const float4*)(logits + (size_t)a * NCLS);
    float best = -1e30f;
#pragma unroll
    for (int k = 0; k < 20; ++k) {
        float4 v = p[k];
        best = fmaxf(best, fmaxf(fmaxf(v.x, v.y), fmaxf(v.z, v.w)));
    }
    if (best > CONF) {
        int pos = atomicAdd(cnt, 1);
        if (pos < 8192) {
            unsigned int eb = __float_as_uint(best);
            eb = (eb & 0x80000000u) ? ~eb : (eb | 0x80000000u);  // sortable-ascending encode
            keys[pos] = ((unsigned long long)eb << 32) | (unsigned int)(~a);
        }
    }
}

// ---------------- Kernel 2: single-block bitonic sort of 4096 keys, descending
__global__ __launch_bounds__(1024) void k_sort(const int* __restrict__ cnt,
                                               const unsigned long long* __restrict__ keys_raw,
                                               unsigned long long* __restrict__ keys_sorted) {
    __shared__ unsigned long long sk[4096];
    int n = min(*cnt, 4096);
    for (int i = threadIdx.x; i < 4096; i += 1024)
        sk[i] = (i < n) ? keys_raw[i] : 0ull;   // sentinel 0 < any valid key (valid >= 2^63)
    __syncthreads();
    for (int k = 2; k <= 4096; k <<= 1) {
        for (int j = k >> 1; j > 0; j >>= 1) {
            for (int i = threadIdx.x; i < 4096; i += 1024) {
                int ixj = i ^ j;
                if (ixj > i) {
                    unsigned long long a = sk[i], b = sk[ixj];
                    bool desc = ((i & k) == 0);
                    if (desc ? (a < b) : (a > b)) { sk[i] = b; sk[ixj] = a; }
                }
            }
            __syncthreads();
        }
    }
    for (int i = threadIdx.x; i < 4096; i += 1024)
        keys_sorted[i] = sk[i];
}

// ---------------- Kernel 3: gather/stage top-K (recompute argmax per top anchor)
__global__ __launch_bounds__(256) void k_gather(const int* __restrict__ cnt,
                                                const unsigned long long* __restrict__ keys_sorted,
                                                const float* __restrict__ logits,
                                                const float* __restrict__ boxes,
                                                float4* __restrict__ topbox,
                                                int* __restrict__ topcat,
                                                int* __restrict__ topcls,
                                                float* __restrict__ topscore,
                                                int* __restrict__ topimg) {
    int s = blockIdx.x * 256 + threadIdx.x;  // 0..4095
    int n = min(*cnt, 4096);
    float4 bx = make_float4(0.f, 0.f, 0.f, 0.f);
    int cat = -1, cls = -1, img = -1;
    float sc = 0.f;
    if (s < n) {
        unsigned long long key = keys_sorted[s];
        unsigned int idx = ~(unsigned int)(key & 0xffffffffu);
        const float4* p = (const float4*)(logits + (size_t)idx * NCLS);
        float best = -1e30f; int bc = 0;
#pragma unroll
        for (int k = 0; k < 20; ++k) {
            float4 v = p[k];
            if (v.x > best) { best = v.x; bc = 4 * k; }
            if (v.y > best) { best = v.y; bc = 4 * k + 1; }
            if (v.z > best) { best = v.z; bc = 4 * k + 2; }
            if (v.w > best) { best = v.w; bc = 4 * k + 3; }
        }
        int b = idx >> 16;     // idx / NPTS, NPTS = 65536
        cls = bc;
        cat = bc + b * NCLS;
        img = b;
        sc  = best;
        bx  = ((const float4*)boxes)[idx];
    }
    topbox[s] = bx; topcat[s] = cat; topcls[s] = cls; topscore[s] = sc; topimg[s] = img;
}

// ---------------- Kernel 4: suppression bitmask tiles (64 rows x 64 cols per block)
__global__ __launch_bounds__(64) void k_mask(const int* __restrict__ cnt,
                                             const float4* __restrict__ topbox,
                                             const int* __restrict__ topcat,
                                             unsigned long long* __restrict__ mask) {
    int n = min(*cnt, 4096);
    int bi = blockIdx.x, bj = blockIdx.y;
    if (bi * 64 >= n || bj * 64 >= n) return;   // unused tiles never read meaningfully
    __shared__ float4 jb[64];
    __shared__ int    jc[64];
    int t = threadIdx.x;
    jb[t] = topbox[bj * 64 + t];
    jc[t] = topcat[bj * 64 + t];
    __syncthreads();
    int i = bi * 64 + t;
    float4 mb = topbox[i];
    int    mc = topcat[i];
    float area_i = (mb.z - mb.x) * (mb.w - mb.y);
    unsigned long long bits = 0ull;
#pragma unroll 4
    for (int jj = 0; jj < 64; ++jj) {
        int j = bj * 64 + jj;
        if (j > i && jc[jj] == mc) {
            float4 ob = jb[jj];
            float iw = fmaxf(fminf(mb.z, ob.z) - fmaxf(mb.x, ob.x), 0.f);
            float ih = fmaxf(fminf(mb.w, ob.w) - fmaxf(mb.y, ob.y), 0.f);
            float inter = iw * ih;
            float aj  = (ob.z - ob.x) * (ob.w - ob.y);
            float uni = area_i + aj - inter;
            float iou = inter / fmaxf(uni, 1e-12f);
            if (iou > NMSTH) bits |= (1ull << jj);
        }
    }
    mask[(size_t)i * 64 + bj] = bits;
}

// ---------------- Kernel 5: serial greedy scan (wave 0) + output write (all 1024)
__global__ __launch_bounds__(1024) void k_nms(const int* __restrict__ cnt,
                                              const unsigned long long* __restrict__ mask,
                                              const float4* __restrict__ topbox,
                                              const int* __restrict__ topcls,
                                              const float* __restrict__ topscore,
                                              const int* __restrict__ topimg,
                                              float* __restrict__ out) {
    __shared__ unsigned long long kws[64];
    int n = min(*cnt, 4096);
    int tid = threadIdx.x;
    if (tid < 64) {
        int t = tid;
        int lo = t * 64;
        unsigned long long kw;
        if (lo + 64 <= n)      kw = ~0ull;
        else if (lo >= n)      kw = 0ull;
        else                   kw = (1ull << (n - lo)) - 1ull;

        // 8-deep prefetch ring of mask rows to hide L2 latency in the serial chain
        unsigned long long r0, r1, r2, r3, r4, r5, r6, r7;
        r0 = (0 < n) ? mask[(size_t)0 * 64 + t] : 0ull;
        r1 = (1 < n) ? mask[(size_t)1 * 64 + t] : 0ull;
        r2 = (2 < n) ? mask[(size_t)2 * 64 + t] : 0ull;
        r3 = (3 < n) ? mask[(size_t)3 * 64 + t] : 0ull;
        r4 = (4 < n) ? mask[(size_t)4 * 64 + t] : 0ull;
        r5 = (5 < n) ? mask[(size_t)5 * 64 + t] : 0ull;
        r6 = (6 < n) ? mask[(size_t)6 * 64 + t] : 0ull;
        r7 = (7 < n) ? mask[(size_t)7 * 64 + t] : 0ull;

        for (int i0 = 0; i0 < n; i0 += 8) {
#define NMS_STEP(K, RK)                                                        \
            {                                                                  \
                int i = i0 + K;                                                \
                if (i < n) {                                                   \
                    unsigned long long cur = RK;                               \
                    int ip = i + 8;                                            \
                    RK = (ip < n) ? mask[(size_t)ip * 64 + t] : 0ull;          \
                    unsigned long long w = __shfl(kw, i >> 6);                 \
                    if ((w >> (i & 63)) & 1ull) kw &= ~cur;                    \
                }                                                              \
            }
            NMS_STEP(0, r0) NMS_STEP(1, r1) NMS_STEP(2, r2) NMS_STEP(3, r3)
            NMS_STEP(4, r4) NMS_STEP(5, r5) NMS_STEP(6, r6) NMS_STEP(7, r7)
#undef NMS_STEP
        }
        kws[t] = kw;
    }
    __syncthreads();

    // outputs: [img 4096][boxes 16384][cls 4096][score 4096], all float32
    for (int s = tid; s < 4096; s += 1024) {
        bool keep = (kws[s >> 6] >> (s & 63)) & 1ull;
        float4 b = topbox[s];
        out[s] = keep ? (float)topimg[s] : -1.0f;
        float4* ob = (float4*)(out + 4096);
        ob[s] = keep ? b : make_float4(0.f, 0.f, 0.f, 0.f);
        out[4096 + 16384 + s]        = keep ? (float)topcls[s] : -1.0f;
        out[4096 + 16384 + 4096 + s] = keep ? topscore[s] : 0.0f;
    }
}

extern "C" void kernel_launch(void* const* d_in, const int* in_sizes, int n_in,
                              void* d_out, int out_size, void* d_ws, size_t ws_size,
                              hipStream_t stream) {
    const float* logits = (const float*)d_in[0];
    const float* boxes  = (const float*)d_in[1];
    float* out = (float*)d_out;
    char* ws = (char*)d_ws;

    int*                cnt         = (int*)(ws + OFF_CNT);
    unsigned long long* keys_raw    = (unsigned long long*)(ws + OFF_KEYS);
    unsigned long long* keys_sorted = (unsigned long long*)(ws + OFF_SORTED);
    float4*             topbox      = (float4*)(ws + OFF_BOX);
    int*                topcat      = (int*)(ws + OFF_CAT);
    int*                topcls      = (int*)(ws + OFF_CLS);
    float*              topscore    = (float*)(ws + OFF_SCORE);
    int*                topimg      = (int*)(ws + OFF_IMG);
    unsigned long long* mask        = (unsigned long long*)(ws + OFF_MASK);

    hipMemsetAsync(cnt, 0, 64, stream);
    k_score<<<NANCH / 256, 256, 0, stream>>>(logits, cnt, keys_raw);
    k_sort<<<1, 1024, 0, stream>>>(cnt, keys_raw, keys_sorted);
    k_gather<<<TOPK / 256, 256, 0, stream>>>(cnt, keys_sorted, logits, boxes,
                                             topbox, topcat, topcls, topscore, topimg);
    dim3 g4(64, 64);
    k_mask<<<g4, 64, 0, stream>>>(cnt, topbox, topcat, mask);
    k_nms<<<1, 1024, 0, stream>>>(cnt, mask, topbox, topcls, topscore, topimg, out);
}

// Round 2
// 384.093 us; speedup vs baseline: 2.2278x; 2.2278x over previous
//
#include <hip/hip_runtime.h>
#include <stdint.h>

// Problem constants (fixed by reference setup_inputs)
#define BATCH  8
#define NPTS   65536
#define NCLS   80
#define NANCH  (BATCH * NPTS)          // 524288
#define TOPK   4096
#define CONF   4.0f
#define NMSTH  0.5f
#define SUPMAX 8

typedef unsigned long long u64;

// ws layout (bytes)
static constexpr size_t OFF_CNT    = 0;                          // int cnt (64B pad)
static constexpr size_t OFF_KEYS   = 64;                         // u64 keys_raw[8192]
static constexpr size_t OFF_SORTED = OFF_KEYS + 8192 * 8;        // u64 keys_sorted[4096]
static constexpr size_t OFF_BOX    = OFF_SORTED + 4096 * 8;      // float4 g_box[4096]
static constexpr size_t OFF_SUP    = OFF_BOX + 4096 * 16;        // u16 g_sup[4096*SUPMAX]

// ---------------- Kernel 1: per-anchor max/argmax + confidence compaction ----
// 4 lanes per anchor -> each float4 load instr covers 16 contiguous 64B segments.
// key = sortable(score):32 | (~idx & 0x7FFFF):19 | cls:7
//   descending key order == (score desc, idx asc); cls doesn't affect order (idx unique).
__global__ __launch_bounds__(256) void k_score(const float* __restrict__ logits,
                                               int* __restrict__ cnt,
                                               u64* __restrict__ keys) {
    int t = threadIdx.x;
    int q = t & 3;                         // sub-lane within anchor
    int a = blockIdx.x * 64 + (t >> 2);    // anchor id (grid exactly covers NANCH)
    const float* base = logits + (size_t)a * NCLS;
    float bv = -1e30f; int bc = 0;
#pragma unroll
    for (int j = 0; j < 5; ++j) {
        float4 v = *(const float4*)(base + q * 4 + j * 16);
        int c0 = q * 4 + j * 16;
        if (v.x > bv) { bv = v.x; bc = c0; }
        if (v.y > bv) { bv = v.y; bc = c0 + 1; }
        if (v.z > bv) { bv = v.z; bc = c0 + 2; }
        if (v.w > bv) { bv = v.w; bc = c0 + 3; }
    }
    // reduce (max, first-argmax) over the 4 lanes of this anchor
#pragma unroll
    for (int d = 1; d <= 2; d <<= 1) {
        float ov = __shfl_xor(bv, d);
        int   oc = __shfl_xor(bc, d);
        if (ov > bv || (ov == bv && oc < bc)) { bv = ov; bc = oc; }
    }
    if (q == 0 && bv > CONF) {
        int pos = atomicAdd(cnt, 1);
        if (pos < 8192) {
            unsigned int eb = __float_as_uint(bv);
            eb = (eb & 0x80000000u) ? ~eb : (eb | 0x80000000u);   // sortable encode
            unsigned int low = (((~(unsigned)a) & 0x7FFFFu) << 7) | (unsigned)bc;
            keys[pos] = ((u64)eb << 32) | low;
        }
    }
}

// ---------------- Kernel 2: single-block bitonic sort (descending) over next_pow2(n)
__global__ __launch_bounds__(1024) void k_sort(const int* __restrict__ cnt,
                                               const u64* __restrict__ keys_raw,
                                               u64* __restrict__ keys_sorted) {
    __shared__ u64 sk[4096];
    int n = min(*cnt, 4096);
    int n2 = 64; while (n2 < n) n2 <<= 1;
    for (int i = threadIdx.x; i < n2; i += 1024)
        sk[i] = (i < n) ? keys_raw[i] : 0ull;   // sentinel 0 < any valid key (valid >= 2^63)
    __syncthreads();
    for (int k = 2; k <= n2; k <<= 1) {
        for (int j = k >> 1; j > 0; j >>= 1) {
            for (int i = threadIdx.x; i < n2; i += 1024) {
                int ixj = i ^ j;
                if (ixj > i) {
                    u64 x = sk[i], y = sk[ixj];
                    bool desc = ((i & k) == 0);
                    if (desc ? (x < y) : (x > y)) { sk[i] = y; sk[ixj] = x; }
                }
            }
            __syncthreads();
        }
    }
    for (int i = threadIdx.x; i < n2; i += 1024)
        keys_sorted[i] = sk[i];
}

// ---------------- Kernel 3: decode + gather + per-category DAG NMS + outputs ----
// Greedy NMS decomposes exactly by category (suppression needs cat equality).
// Build per-item suppressor-candidate lists (rare), then resolve the DAG
// iteratively (monotone fixpoint == greedy result; converges in ~2 rounds).
__global__ __launch_bounds__(1024) void k_nms(const int* __restrict__ cnt,
                                              const u64* __restrict__ keys_sorted,
                                              const float* __restrict__ boxes,
                                              float4* __restrict__ g_box,
                                              unsigned short* __restrict__ g_sup,
                                              float* __restrict__ out) {
    __shared__ float4 s_box[2048];             // boxes for j-side reads (n<=2048 fast path)
    __shared__ int    s_cat[4096];
    __shared__ unsigned char s_state[4096];    // 0=dead/invalid 1=kept 2=pending
    __shared__ int s_changed;
    int n = min(*cnt, 4096);
    int tid = threadIdx.x;

    float4 bx[4]; int cat[4], cls[4], img[4]; float sc[4];
#pragma unroll
    for (int r = 0; r < 4; ++r) {
        int s = tid + 1024 * r;
        float4 b = make_float4(0.f, 0.f, 0.f, 0.f);
        int ct = -1, cl = -1, im = -1; float v = 0.f;
        if (s < n) {
            u64 key = keys_sorted[s];
            unsigned int eb = (unsigned int)(key >> 32);
            unsigned int orig = (eb & 0x80000000u) ? (eb & 0x7fffffffu) : ~eb;
            v = __uint_as_float(orig);
            unsigned int low = (unsigned int)key;
            cl = (int)(low & 0x7fu);
            unsigned int a = (~(low >> 7)) & 0x7FFFFu;
            im = (int)(a >> 16);               // a / NPTS
            ct = cl + im * NCLS;
            b = ((const float4*)boxes)[a];
        }
        bx[r] = b; cat[r] = ct; cls[r] = cl; img[r] = im; sc[r] = v;
        if (s < 2048) s_box[s] = b;
        g_box[s] = b;
        s_cat[s] = ct;
    }
    __syncthreads();

    // pair sweep: suppressor candidates j < s, same cat, IoU > 0.5
    int supcnt[4] = {0, 0, 0, 0};
#pragma unroll
    for (int r = 0; r < 4; ++r) {
        int s = tid + 1024 * r;
        if (s >= n) continue;
        float ax1 = bx[r].x, ay1 = bx[r].y, ax2 = bx[r].z, ay2 = bx[r].w;
        float areai = (ax2 - ax1) * (ay2 - ay1);
        int myc = cat[r];
        for (int m = 0; m < s; ++m) {
            if (s_cat[m] == myc) {             // rare (~2 per item)
                float4 ob = (m < 2048) ? s_box[m] : g_box[m];
                float iw = fmaxf(fminf(ax2, ob.z) - fmaxf(ax1, ob.x), 0.f);
                float ih = fmaxf(fminf(ay2, ob.w) - fmaxf(ay1, ob.y), 0.f);
                float inter = iw * ih;
                float aj  = (ob.z - ob.x) * (ob.w - ob.y);
                float uni = areai + aj - inter;
                if (inter / fmaxf(uni, 1e-12f) > NMSTH) {
                    if (supcnt[r] < SUPMAX)
                        g_sup[(size_t)s * SUPMAX + supcnt[r]] = (unsigned short)m;
                    supcnt[r]++;
                }
            }
        }
    }
#pragma unroll
    for (int r = 0; r < 4; ++r) {
        int s = tid + 1024 * r;
        s_state[s] = (s < n) ? (supcnt[r] ? 2 : 1) : 0;
    }
    __syncthreads();

    // resolve dependency DAG (unique greedy fixpoint; races only speed it up)
    if (tid == 0) s_changed = 0;
    __syncthreads();
    while (true) {
        bool pend_mine = false;
#pragma unroll
        for (int r = 0; r < 4; ++r) {
            int s = tid + 1024 * r;
            if (s < n && s_state[s] == 2) {
                bool anyKept = false, anyPend = false;
                int c = min(supcnt[r], SUPMAX);
                for (int m = 0; m < c; ++m) {
                    unsigned char st = s_state[g_sup[(size_t)s * SUPMAX + m]];
                    anyKept |= (st == 1);
                    anyPend |= (st == 2);
                }
                if (anyKept)       s_state[s] = 0;
                else if (!anyPend) s_state[s] = 1;
                else               pend_mine = true;
            }
        }
        if (pend_mine) s_changed = 1;
        __syncthreads();
        int ch = s_changed;
        __syncthreads();
        if (!ch) break;
        if (tid == 0) s_changed = 0;
        __syncthreads();
    }

    // outputs: [img 4096][boxes 16384][cls 4096][score 4096], all float32
#pragma unroll
    for (int r = 0; r < 4; ++r) {
        int s = tid + 1024 * r;
        bool keep = (s_state[s] == 1);
        out[s] = keep ? (float)img[r] : -1.0f;
        ((float4*)(out + 4096))[s] = keep ? bx[r] : make_float4(0.f, 0.f, 0.f, 0.f);
        out[4096 + 16384 + s]        = keep ? (float)cls[r] : -1.0f;
        out[4096 + 16384 + 4096 + s] = keep ? sc[r] : 0.0f;
    }
}

extern "C" void kernel_launch(void* const* d_in, const int* in_sizes, int n_in,
                              void* d_out, int out_size, void* d_ws, size_t ws_size,
                              hipStream_t stream) {
    const float* logits = (const float*)d_in[0];
    const float* boxes  = (const float*)d_in[1];
    float* out = (float*)d_out;
    char* ws = (char*)d_ws;

    int*            cnt         = (int*)(ws + OFF_CNT);
    u64*            keys_raw    = (u64*)(ws + OFF_KEYS);
    u64*            keys_sorted = (u64*)(ws + OFF_SORTED);
    float4*         g_box       = (float4*)(ws + OFF_BOX);
    unsigned short* g_sup       = (unsigned short*)(ws + OFF_SUP);

    hipMemsetAsync(cnt, 0, 64, stream);
    k_score<<<NANCH / 64, 256, 0, stream>>>(logits, cnt, keys_raw);
    k_sort<<<1, 1024, 0, stream>>>(cnt, keys_raw, keys_sorted);
    k_nms<<<1, 1024, 0, stream>>>(cnt, keys_sorted, boxes, g_box, g_sup, out);
}

// Round 3
// 281.898 us; speedup vs baseline: 3.0354x; 1.3625x over previous
//
#include <hip/hip_runtime.h>
#include <stdint.h>

typedef unsigned long long u64;
typedef unsigned int u32;

// Problem constants (fixed by reference setup_inputs)
#define BATCH  8
#define NPTS   65536
#define NCLS   80
#define NANCH  (BATCH * NPTS)          // 524288
#define TOPK   4096
#define CONF   4.0f
#define NMSTH  0.5f
#define NCAT   (BATCH * NCLS)          // 640
#define BCAP   32                      // bucket capacity (Poisson lambda~2.1; P(>=32) ~ 1e-25)

// ws layout (bytes)
static constexpr size_t OFF_CNT    = 0;                          // int cnt (64B pad)
static constexpr size_t OFF_KEYS   = 64;                         // u64 keys_raw[8192]
static constexpr size_t OFF_SORTED = OFF_KEYS + 8192 * 8;        // u64 keys_sorted[4096]

// ---------------- Kernel 1: per-anchor max/argmax + confidence compaction ----
// One wave per 64 anchors = 20480 contiguous bytes. 20 loads/lane at
// lane*16 + k*1024 -> every load instr covers 1024 contiguous bytes (perfect
// coalescing). Each float4 belongs to exactly one anchor (320 % 16 == 0):
// linear float4 index e = k*64+lane -> anchor e/20, sub-slot e%20.
// Per-float4 (max, argmax) packed into u64 = sortable(score):32 | (255-cls):8
// (u64 max == (score desc, cls asc) — matches jnp.argmax first-wins on ties),
// staged in LDS with 21-u64 anchor stride (odd -> only 4-way b64 read alias),
// then lane L max-reduces its anchor's 20 slots.
__global__ __launch_bounds__(64) void k_score(const float* __restrict__ logits,
                                              int* __restrict__ cnt,
                                              u64* __restrict__ keys) {
    __shared__ u64 red[64 * 21];
    int lane = threadIdx.x;
    const float4* src = (const float4*)logits + (size_t)blockIdx.x * 1280;
#pragma unroll
    for (int k = 0; k < 20; ++k) {
        int e = k * 64 + lane;
        float4 v = src[e];
        float bv = v.x; int bc = 0;
        if (v.y > bv) { bv = v.y; bc = 1; }
        if (v.z > bv) { bv = v.z; bc = 2; }
        if (v.w > bv) { bv = v.w; bc = 3; }
        int a_l = e / 20;
        int j   = e % 20;
        int cls = j * 4 + bc;
        u32 eb = __float_as_uint(bv);
        eb = (eb & 0x80000000u) ? ~eb : (eb | 0x80000000u);   // sortable-ascending encode
        red[a_l * 21 + j] = ((u64)eb << 32) | (u32)(255 - cls);
    }
    __syncthreads();
    u64 best = 0;
#pragma unroll
    for (int j = 0; j < 20; ++j) {
        u64 p = red[lane * 21 + j];
        best = (p > best) ? p : best;
    }
    u32 eb = (u32)(best >> 32);
    u32 orig = (eb & 0x80000000u) ? (eb & 0x7fffffffu) : ~eb;
    float sc = __uint_as_float(orig);
    if (sc > CONF) {
        int pos = atomicAdd(cnt, 1);
        if (pos < 8192) {
            u32 cls = 255u - (u32)(best & 0xffu);
            u32 a = blockIdx.x * 64 + lane;
            u64 low = (((~a) & 0x7FFFFu) << 7) | cls;
            keys[pos] = ((u64)eb << 32) | low;   // key order == (score desc, idx asc)
        }
    }
}

// ---------------- Kernel 2: single-block bitonic sort (descending) over next_pow2(n)
__global__ __launch_bounds__(1024) void k_sort(const int* __restrict__ cnt,
                                               const u64* __restrict__ keys_raw,
                                               u64* __restrict__ keys_sorted) {
    __shared__ u64 sk[4096];
    int n = min(*cnt, 4096);
    int n2 = 64; while (n2 < n) n2 <<= 1;
    for (int i = threadIdx.x; i < n2; i += 1024)
        sk[i] = (i < n) ? keys_raw[i] : 0ull;   // sentinel 0 < any valid key (valid >= 2^63)
    __syncthreads();
    for (int k = 2; k <= n2; k <<= 1) {
        for (int j = k >> 1; j > 0; j >>= 1) {
            for (int i = threadIdx.x; i < n2; i += 1024) {
                int ixj = i ^ j;
                if (ixj > i) {
                    u64 x = sk[i], y = sk[ixj];
                    bool desc = ((i & k) == 0);
                    if (desc ? (x < y) : (x > y)) { sk[i] = y; sk[ixj] = x; }
                }
            }
            __syncthreads();
        }
    }
    for (int i = threadIdx.x; i < n2; i += 1024)
        keys_sorted[i] = sk[i];
}

// ---------------- Kernel 3: decode + gather + per-category exact greedy NMS ----
// Suppression requires cat[i]==cat[j], so global greedy NMS == independent
// greedy per category. Bucket items by cat (640 buckets, ~2 items each),
// then one thread per category replays the exact sequential greedy on its
// bucket (rank order = slot order; only kept items suppress).
__global__ __launch_bounds__(1024) void k_nms(const int* __restrict__ cnt,
                                              const u64* __restrict__ keys_sorted,
                                              const float* __restrict__ boxes,
                                              float* __restrict__ out) {
    __shared__ float4 s_box[4096];                    // 64 KB
    __shared__ unsigned short s_bucket[NCAT * BCAP];  // 40 KB
    __shared__ int s_bcnt[NCAT];                      // 2.5 KB
    __shared__ unsigned char s_keep[4096];            // 4 KB
    int n = min(*cnt, TOPK);
    int tid = threadIdx.x;

    for (int c = tid; c < NCAT; c += 1024) s_bcnt[c] = 0;

    float4 bx[4]; int cls_[4], img_[4]; float sc_[4];
#pragma unroll
    for (int r = 0; r < 4; ++r) {
        int s = tid + 1024 * r;
        float4 b = make_float4(0.f, 0.f, 0.f, 0.f);
        int cl = -1, im = -1; float v = 0.f;
        if (s < n) {
            u64 key = keys_sorted[s];
            u32 eb = (u32)(key >> 32);
            u32 orig = (eb & 0x80000000u) ? (eb & 0x7fffffffu) : ~eb;
            v = __uint_as_float(orig);
            u32 low = (u32)key;
            cl = (int)(low & 0x7fu);
            u32 a = (~(low >> 7)) & 0x7FFFFu;
            im = (int)(a >> 16);                      // a / NPTS
            b = ((const float4*)boxes)[a];
        }
        bx[r] = b; cls_[r] = cl; img_[r] = im; sc_[r] = v;
        s_box[s]  = b;
        s_keep[s] = (s < n) ? 1 : 0;
    }
    __syncthreads();

    // bucket fill (order within bucket irrelevant; sorted by rank below)
#pragma unroll
    for (int r = 0; r < 4; ++r) {
        int s = tid + 1024 * r;
        if (s < n) {
            int c = img_[r] * NCLS + cls_[r];
            int pos = atomicAdd(&s_bcnt[c], 1);
            if (pos < BCAP) s_bucket[c * BCAP + pos] = (unsigned short)s;
        }
    }
    __syncthreads();

    // per-category exact greedy (disjoint buckets -> no cross-thread races)
    if (tid < NCAT) {
        int m = min(s_bcnt[tid], BCAP);
        unsigned short* bkt = &s_bucket[tid * BCAP];
        if (m > 1) {
            // insertion sort ascending by rank s (in LDS — avoids scratch spill)
            for (int i = 1; i < m; ++i) {
                unsigned short x = bkt[i]; int j = i - 1;
                while (j >= 0 && bkt[j] > x) { bkt[j + 1] = bkt[j]; --j; }
                bkt[j + 1] = x;
            }
            for (int i = 1; i < m; ++i) {
                float4 bi = s_box[bkt[i]];
                float areai = (bi.z - bi.x) * (bi.w - bi.y);
                bool dead = false;
                for (int j = 0; j < i && !dead; ++j) {
                    if (!s_keep[bkt[j]]) continue;    // only kept items suppress
                    float4 bj = s_box[bkt[j]];
                    float iw = fmaxf(fminf(bi.z, bj.z) - fmaxf(bi.x, bj.x), 0.f);
                    float ih = fmaxf(fminf(bi.w, bj.w) - fmaxf(bi.y, bj.y), 0.f);
                    float inter = iw * ih;
                    float uni = areai + (bj.z - bj.x) * (bj.w - bj.y) - inter;
                    if (inter / fmaxf(uni, 1e-12f) > NMSTH) dead = true;
                }
                if (dead) s_keep[bkt[i]] = 0;
            }
        }
    }
    __syncthreads();

    // outputs: [img 4096][boxes 16384][cls 4096][score 4096], all float32
#pragma unroll
    for (int r = 0; r < 4; ++r) {
        int s = tid + 1024 * r;
        bool keep = s_keep[s] != 0;
        out[s] = keep ? (float)img_[r] : -1.0f;
        ((float4*)(out + 4096))[s] = keep ? bx[r] : make_float4(0.f, 0.f, 0.f, 0.f);
        out[4096 + 16384 + s]        = keep ? (float)cls_[r] : -1.0f;
        out[4096 + 16384 + 4096 + s] = keep ? sc_[r] : 0.0f;
    }
}

extern "C" void kernel_launch(void* const* d_in, const int* in_sizes, int n_in,
                              void* d_out, int out_size, void* d_ws, size_t ws_size,
                              hipStream_t stream) {
    const float* logits = (const float*)d_in[0];
    const float* boxes  = (const float*)d_in[1];
    float* out = (float*)d_out;
    char* ws = (char*)d_ws;

    int* cnt         = (int*)(ws + OFF_CNT);
    u64* keys_raw    = (u64*)(ws + OFF_KEYS);
    u64* keys_sorted = (u64*)(ws + OFF_SORTED);

    hipMemsetAsync(cnt, 0, 64, stream);
    k_score<<<NANCH / 64, 64, 0, stream>>>(logits, cnt, keys_raw);
    k_sort<<<1, 1024, 0, stream>>>(cnt, keys_raw, keys_sorted);
    k_nms<<<1, 1024, 0, stream>>>(cnt, keys_sorted, boxes, out);
}

// Round 4
// 269.190 us; speedup vs baseline: 3.1787x; 1.0472x over previous
//
#include <hip/hip_runtime.h>
#include <stdint.h>

typedef unsigned long long u64;
typedef unsigned int u32;
typedef float fv4 __attribute__((ext_vector_type(4)));

// Problem constants (fixed by reference setup_inputs)
#define BATCH  8
#define NPTS   65536
#define NCLS   80
#define NANCH  (BATCH * NPTS)          // 524288
#define TOPK   4096
#define CONF   4.0f
#define NMSTH  0.5f
#define NCAT   (BATCH * NCLS)          // 640
#define BCAP   32                      // bucket capacity (Poisson lambda~2.1; P(>=32) ~ 1e-25)

// ws layout (bytes)
static constexpr size_t OFF_CNT  = 0;     // int cnt (64B pad)
static constexpr size_t OFF_KEYS = 64;    // u64 keys_raw[8192]

// ---------------- Kernel 1: per-anchor max/argmax + confidence compaction ----
// One wave per 64 anchors = 20480 contiguous bytes, 20 perfectly-coalesced
// nontemporal float4 loads per lane (logits are streamed exactly once).
// Transpose via LDS with SPLIT arrays:
//   s_sc: u32 sortable score, anchor stride 21 (odd) -> conflict-free b32
//   s_cl: u8 in-slot argmax class, read once at the end
// Reduce: first slot j attaining the max holds the lowest class attaining the
// global max (slots ascend in class; in-slot argmax is first-wins) -> exact
// jnp.argmax tie semantics.
__global__ __launch_bounds__(64) void k_score(const float* __restrict__ logits,
                                              int* __restrict__ cnt,
                                              u64* __restrict__ keys) {
    __shared__ u32 s_sc[64 * 21];
    __shared__ unsigned char s_cl[64 * 20];
    int lane = threadIdx.x;
    const fv4* src = (const fv4*)logits + (size_t)blockIdx.x * 1280;
#pragma unroll
    for (int k = 0; k < 20; ++k) {
        int e = k * 64 + lane;
        fv4 v = __builtin_nontemporal_load(&src[e]);
        float bv = v.x; int bc = 0;
        if (v.y > bv) { bv = v.y; bc = 1; }
        if (v.z > bv) { bv = v.z; bc = 2; }
        if (v.w > bv) { bv = v.w; bc = 3; }
        int a_l = e / 20, j = e % 20;
        u32 eb = __float_as_uint(bv);
        eb = (eb & 0x80000000u) ? ~eb : (eb | 0x80000000u);   // sortable-ascending encode
        s_sc[a_l * 21 + j] = eb;
        s_cl[a_l * 20 + j] = (unsigned char)(j * 4 + bc);
    }
    __syncthreads();
    u32 best = 0; int bj = 0;
#pragma unroll
    for (int j = 0; j < 20; ++j) {
        u32 p = s_sc[lane * 21 + j];
        if (p > best) { best = p; bj = j; }   // strict > : first max slot wins
    }
    u32 orig = (best & 0x80000000u) ? (best & 0x7fffffffu) : ~best;
    if (__uint_as_float(orig) > CONF) {
        u32 cls = s_cl[lane * 20 + bj];
        u32 a = blockIdx.x * 64 + (u32)lane;
        int pos = atomicAdd(cnt, 1);
        if (pos < 8192)
            keys[pos] = ((u64)best << 32) | ((((~a) & 0x7FFFFu) << 7) | cls);
        // key order == (score desc, idx asc); cls bits don't disturb (idx unique)
    }
}

// ---------------- Kernel 2: sort + decode + gather + per-category greedy NMS ----
// Bitonic sort fused in (next_pow2(n) elements, in-LDS). Then: suppression
// requires cat[i]==cat[j], so global greedy NMS == independent greedy per
// category. Bucket items by cat (640 buckets, ~2 items each), one thread per
// category replays the exact sequential greedy on its bucket.
__global__ __launch_bounds__(1024) void k_nms(const int* __restrict__ cnt,
                                              const u64* __restrict__ keys_raw,
                                              const float* __restrict__ boxes,
                                              float* __restrict__ out) {
    __shared__ u64    s_keys[4096];                   // 32 KB
    __shared__ float4 s_box[4096];                    // 64 KB
    __shared__ unsigned short s_bucket[NCAT * BCAP];  // 40 KB
    __shared__ int s_bcnt[NCAT];                      // 2.5 KB
    __shared__ unsigned char s_keep[4096];            // 4 KB
    int n = min(*cnt, TOPK);
    int tid = threadIdx.x;
    int n2 = 64; while (n2 < n) n2 <<= 1;

    for (int c = tid; c < NCAT; c += 1024) s_bcnt[c] = 0;
    for (int i = tid; i < n2; i += 1024)
        s_keys[i] = (i < n) ? keys_raw[i] : 0ull;   // sentinel 0 < any valid key (valid >= 2^63)
    __syncthreads();

    // bitonic, descending
    for (int k = 2; k <= n2; k <<= 1) {
        for (int j = k >> 1; j > 0; j >>= 1) {
            for (int i = tid; i < n2; i += 1024) {
                int ixj = i ^ j;
                if (ixj > i) {
                    u64 x = s_keys[i], y = s_keys[ixj];
                    bool desc = ((i & k) == 0);
                    if (desc ? (x < y) : (x > y)) { s_keys[i] = y; s_keys[ixj] = x; }
                }
            }
            __syncthreads();
        }
    }

    // decode + gather boxes + fill category buckets
    float4 bx[4]; int cls_[4], img_[4]; float sc_[4];
#pragma unroll
    for (int r = 0; r < 4; ++r) {
        int s = tid + 1024 * r;
        float4 b = make_float4(0.f, 0.f, 0.f, 0.f);
        int cl = -1, im = -1; float v = 0.f;
        if (s < n) {
            u64 key = s_keys[s];
            u32 eb = (u32)(key >> 32);
            u32 orig = (eb & 0x80000000u) ? (eb & 0x7fffffffu) : ~eb;
            v = __uint_as_float(orig);
            u32 low = (u32)key;
            cl = (int)(low & 0x7fu);
            u32 a = (~(low >> 7)) & 0x7FFFFu;
            im = (int)(a >> 16);                      // a / NPTS
            b = ((const float4*)boxes)[a];
            int c = im * NCLS + cl;
            int pos = atomicAdd(&s_bcnt[c], 1);
            if (pos < BCAP) s_bucket[c * BCAP + pos] = (unsigned short)s;
        }
        bx[r] = b; cls_[r] = cl; img_[r] = im; sc_[r] = v;
        s_box[s]  = b;
        s_keep[s] = (s < n) ? 1 : 0;
    }
    __syncthreads();

    // per-category exact greedy (disjoint buckets -> no cross-thread races)
    if (tid < NCAT) {
        int m = min(s_bcnt[tid], BCAP);
        unsigned short* bkt = &s_bucket[tid * BCAP];
        if (m > 1) {
            // insertion sort ascending by rank s (rank order within category)
            for (int i = 1; i < m; ++i) {
                unsigned short x = bkt[i]; int j = i - 1;
                while (j >= 0 && bkt[j] > x) { bkt[j + 1] = bkt[j]; --j; }
                bkt[j + 1] = x;
            }
            for (int i = 1; i < m; ++i) {
                float4 bi = s_box[bkt[i]];
                float areai = (bi.z - bi.x) * (bi.w - bi.y);
                bool dead = false;
                for (int j = 0; j < i && !dead; ++j) {
                    if (!s_keep[bkt[j]]) continue;    // only kept items suppress
                    float4 bj = s_box[bkt[j]];
                    float iw = fmaxf(fminf(bi.z, bj.z) - fmaxf(bi.x, bj.x), 0.f);
                    float ih = fmaxf(fminf(bi.w, bj.w) - fmaxf(bi.y, bj.y), 0.f);
                    float inter = iw * ih;
                    float uni = areai + (bj.z - bj.x) * (bj.w - bj.y) - inter;
                    if (inter / fmaxf(uni, 1e-12f) > NMSTH) dead = true;
                }
                if (dead) s_keep[bkt[i]] = 0;
            }
        }
    }
    __syncthreads();

    // outputs: [img 4096][boxes 16384][cls 4096][score 4096], all float32
#pragma unroll
    for (int r = 0; r < 4; ++r) {
        int s = tid + 1024 * r;
        bool keep = s_keep[s] != 0;
        out[s] = keep ? (float)img_[r] : -1.0f;
        ((float4*)(out + 4096))[s] = keep ? bx[r] : make_float4(0.f, 0.f, 0.f, 0.f);
        out[4096 + 16384 + s]        = keep ? (float)cls_[r] : -1.0f;
        out[4096 + 16384 + 4096 + s] = keep ? sc_[r] : 0.0f;
    }
}

extern "C" void kernel_launch(void* const* d_in, const int* in_sizes, int n_in,
                              void* d_out, int out_size, void* d_ws, size_t ws_size,
                              hipStream_t stream) {
    const float* logits = (const float*)d_in[0];
    const float* boxes  = (const float*)d_in[1];
    float* out = (float*)d_out;
    char* ws = (char*)d_ws;

    int* cnt      = (int*)(ws + OFF_CNT);
    u64* keys_raw = (u64*)(ws + OFF_KEYS);

    hipMemsetAsync(cnt, 0, 64, stream);
    k_score<<<NANCH / 64, 64, 0, stream>>>(logits, cnt, keys_raw);
    k_nms<<<1, 1024, 0, stream>>>(cnt, keys_raw, boxes, out);
}